// Round 1
// baseline (1585.184 us; speedup 1.0000x reference)
//
#include <hip/hip_runtime.h>
#include <math.h>

#define BB 4
#define SS 1024
#define DM 1024
#define HH 16
#define DKK 64
#define NTOK (BB*SS)   // 4096

// ============================================================
// GEMM: Y = X @ W^T + bias
// X: [M=4096, K=1024] row-major, W: [N=1024, K=1024] row-major.
// HEAD_OUT: write Y[m,o] -> Yh[((b*H + h)*S + s)*DK + dk]  (head-split layout)
// else flat Y[m*1024 + o].
// 64x64 tile, 256 threads, 4x4 micro-tile per thread, K-step 16.
// ============================================================
template<bool HEAD_OUT>
__global__ __launch_bounds__(256) void gemm_xwT(
    const float* __restrict__ X, const float* __restrict__ W,
    const float* __restrict__ bias, float* __restrict__ Y)
{
    __shared__ float Xs[16][68];   // [k][m], pad 68 for b128 alignment + banks
    __shared__ float Ws[16][68];   // [k][o]

    const int tid = threadIdx.x;
    const int to = tid & 15;       // output-col group
    const int tm = tid >> 4;       // output-row group
    const int m0 = blockIdx.y * 64;
    const int o0 = blockIdx.x * 64;

    // loader mapping: thread loads one float4 of X and of W per K-step
    const int lm = tid >> 2;        // 0..63 tile row
    const int lk = (tid & 3) * 4;   // k offset 0,4,8,12

    float acc[4][4] = {};

    for (int kt = 0; kt < 1024; kt += 16) {
        const float4 xa = *(const float4*)&X[(size_t)(m0 + lm) * 1024 + kt + lk];
        const float4 wa = *(const float4*)&W[(size_t)(o0 + lm) * 1024 + kt + lk];
        __syncthreads();   // previous iteration's LDS reads done
        Xs[lk+0][lm] = xa.x; Xs[lk+1][lm] = xa.y; Xs[lk+2][lm] = xa.z; Xs[lk+3][lm] = xa.w;
        Ws[lk+0][lm] = wa.x; Ws[lk+1][lm] = wa.y; Ws[lk+2][lm] = wa.z; Ws[lk+3][lm] = wa.w;
        __syncthreads();
        #pragma unroll
        for (int kk = 0; kk < 16; ++kk) {
            const float4 a4 = *(const float4*)&Xs[kk][tm * 4];
            const float4 b4 = *(const float4*)&Ws[kk][to * 4];
            const float av[4] = {a4.x, a4.y, a4.z, a4.w};
            const float bv[4] = {b4.x, b4.y, b4.z, b4.w};
            #pragma unroll
            for (int i = 0; i < 4; ++i)
                #pragma unroll
                for (int j = 0; j < 4; ++j)
                    acc[i][j] = fmaf(av[i], bv[j], acc[i][j]);
        }
    }

    #pragma unroll
    for (int i = 0; i < 4; ++i) {
        const int m = m0 + tm * 4 + i;
        #pragma unroll
        for (int j = 0; j < 4; ++j) {
            const int o = o0 + to * 4 + j;
            const float val = acc[i][j] + bias[o];
            if (HEAD_OUT) {
                // m = b*S + s ; o = h*DK + dk
                const int b_ = m >> 10, s_ = m & 1023;
                const int h_ = o >> 6,  d_ = o & 63;
                Y[(((size_t)(b_ * HH + h_)) * SS + s_) * DKK + d_] = val;
            } else {
                Y[(size_t)m * 1024 + o] = val;
            }
        }
    }
}

// ============================================================
// Fused attention: scores -> softmax(unmasked) -> masked cumsum ->
// distance-decay -> masked softmax -> PV.
// One wave (64 lanes) per q-row; 4 rows (4 waves) per block.
// ============================================================
__global__ __launch_bounds__(256) void attn_kernel(
    const float* __restrict__ Qh, const float* __restrict__ Kh,
    const float* __restrict__ Vh, const float* __restrict__ gammas,
    float* __restrict__ Ao)
{
    __shared__ float sQ[4][64];
    __shared__ float sK[64][68];     // K tile, pad 68
    __shared__ float sS[4][1024];    // score rows

    const int tid  = threadIdx.x;
    const int lane = tid & 63;
    const int w    = tid >> 6;            // wave id = q-row within tile
    const int bh   = blockIdx.x >> 8;     // 256 q-tiles per (b,h)
    const int qt   = blockIdx.x & 255;
    const int q    = qt * 4 + w;
    const int h    = bh & (HH - 1);
    const int b_   = bh >> 4;

    const float* Qb = Qh + (size_t)bh * SS * DKK;
    const float* Kb = Kh + (size_t)bh * SS * DKK;
    const float* Vb = Vh + (size_t)bh * SS * DKK;

    // gamma = -softplus(gammas[h]), numerically stable
    const float g  = gammas[h];
    const float gamma = -(fmaxf(g, 0.f) + log1pf(expf(-fabsf(g))));

    // ---- load Q rows ----
    sQ[w][lane] = Qb[(size_t)q * DKK + lane];

    // ---- scores: full row (unmasked softmax needs ALL k) ----
    for (int kt = 0; kt < 16; ++kt) {
        __syncthreads();   // previous tile reads done (also covers sQ on kt=0)
        #pragma unroll
        for (int i = 0; i < 4; ++i) {
            const int f  = i * 256 + tid;   // float4 index 0..1023
            const int kk = f >> 4;
            const int d4 = f & 15;
            *(float4*)&sK[kk][d4 * 4] =
                *(const float4*)&Kb[(size_t)((kt * 64 + kk) << 6) + d4 * 4];
        }
        __syncthreads();
        float acc = 0.f;
        #pragma unroll
        for (int d4 = 0; d4 < 16; ++d4) {
            const float4 kv = *(const float4*)&sK[lane][d4 * 4];
            const float4 qv = *(const float4*)&sQ[w][d4 * 4];
            acc = fmaf(kv.x, qv.x, acc); acc = fmaf(kv.y, qv.y, acc);
            acc = fmaf(kv.z, qv.z, acc); acc = fmaf(kv.w, qv.w, acc);
        }
        sS[w][kt * 64 + lane] = acc * 0.125f;   // 1/sqrt(64)
    }
    __syncthreads();

    // ---- pass A: full-row max (interleaved, conflict-free) ----
    float m1 = -INFINITY;
    #pragma unroll
    for (int i = 0; i < 16; ++i) m1 = fmaxf(m1, sS[w][i * 64 + lane]);
    #pragma unroll
    for (int off = 32; off; off >>= 1) m1 = fmaxf(m1, __shfl_xor(m1, off, 64));

    // ---- pass B: full-row sum of exp (unmasked softmax denominator) ----
    float s1 = 0.f;
    #pragma unroll
    for (int i = 0; i < 16; ++i) s1 += expf(sS[w][i * 64 + lane] - m1);
    #pragma unroll
    for (int off = 32; off; off >>= 1) s1 += __shfl_xor(s1, off, 64);
    const float inv_s1 = 1.f / s1;

    // ---- chunked prefix: lane owns k in [lane*16, lane*16+16) ----
    const int kbase = lane * 16;
    float sv[16];
    #pragma unroll
    for (int j4 = 0; j4 < 4; ++j4) {
        const float4 t4 = *(const float4*)&sS[w][kbase + j4 * 4];
        sv[j4*4+0] = t4.x; sv[j4*4+1] = t4.y; sv[j4*4+2] = t4.z; sv[j4*4+3] = t4.w;
    }
    float csum = 0.f;
    float pref[16];
    #pragma unroll
    for (int j = 0; j < 16; ++j) {
        const int k = kbase + j;
        const float p = (k <= q) ? expf(sv[j] - m1) * inv_s1 : 0.f;
        csum += p;
        pref[j] = csum;           // inclusive prefix within chunk
    }
    // wave exclusive scan of chunk sums
    float run = csum;
    #pragma unroll
    for (int off = 1; off < 64; off <<= 1) {
        const float t = __shfl_up(run, off, 64);
        if (lane >= off) run += t;
    }
    const float total = __shfl(run, 63, 64);   // disttotal
    const float excl  = run - csum;

    // ---- distance decay -> s2 (kept in regs) ----
    #pragma unroll
    for (int j = 0; j < 16; ++j) {
        const int k = kbase + j;
        if (k <= q) {
            const float distcum = excl + pref[j];
            const float peff = (float)(q - k);
            const float dsc  = sqrtf(fmaxf((total - distcum) * peff, 0.f));
            const float te   = fminf(fmaxf(expf(dsc * gamma), 1e-5f), 1e5f);
            sv[j] = sv[j] * te;
        } else {
            sv[j] = -INFINITY;
        }
    }

    // ---- masked softmax over s2 ----
    float m2 = -INFINITY;
    #pragma unroll
    for (int j = 0; j < 16; ++j) m2 = fmaxf(m2, sv[j]);
    #pragma unroll
    for (int off = 32; off; off >>= 1) m2 = fmaxf(m2, __shfl_xor(m2, off, 64));
    float ssum = 0.f;
    #pragma unroll
    for (int j = 0; j < 16; ++j) {
        const float e = expf(sv[j] - m2);   // exp(-inf)=0 for masked
        sv[j] = e;
        ssum += e;
    }
    #pragma unroll
    for (int off = 32; off; off >>= 1) ssum += __shfl_xor(ssum, off, 64);
    const float inv2 = 1.f / ssum;
    #pragma unroll
    for (int j4 = 0; j4 < 4; ++j4) {
        float4 o4;
        o4.x = sv[j4*4+0] * inv2; o4.y = sv[j4*4+1] * inv2;
        o4.z = sv[j4*4+2] * inv2; o4.w = sv[j4*4+3] * inv2;
        *(float4*)&sS[w][kbase + j4 * 4] = o4;
    }
    __syncthreads();   // attn row visible to all lanes of the wave

    // ---- PV: out[d=lane] = sum_{k<=q} attn[k] * V[k][d] ----
    float a0 = 0.f, a1 = 0.f, a2 = 0.f, a3 = 0.f;
    const int qe = q + 1;
    int k = 0;
    for (; k + 4 <= qe; k += 4) {
        a0 = fmaf(sS[w][k+0], Vb[(size_t)(k+0) * DKK + lane], a0);
        a1 = fmaf(sS[w][k+1], Vb[(size_t)(k+1) * DKK + lane], a1);
        a2 = fmaf(sS[w][k+2], Vb[(size_t)(k+2) * DKK + lane], a2);
        a3 = fmaf(sS[w][k+3], Vb[(size_t)(k+3) * DKK + lane], a3);
    }
    for (; k < qe; ++k)
        a0 = fmaf(sS[w][k], Vb[(size_t)k * DKK + lane], a0);

    // write to concat layout [B, S, DM]
    Ao[((size_t)(b_ * SS + q)) * DM + h * DKK + lane] = a0 + a1 + a2 + a3;
}

// ============================================================
extern "C" void kernel_launch(void* const* d_in, const int* in_sizes, int n_in,
                              void* d_out, int out_size, void* d_ws, size_t ws_size,
                              hipStream_t stream)
{
    (void)in_sizes; (void)n_in; (void)out_size; (void)ws_size;

    const float* q   = (const float*)d_in[0];
    const float* k   = (const float*)d_in[1];
    const float* v   = (const float*)d_in[2];
    const float* Wq  = (const float*)d_in[3];
    const float* bq  = (const float*)d_in[4];
    const float* Wk  = (const float*)d_in[5];
    const float* bk  = (const float*)d_in[6];
    const float* Wv  = (const float*)d_in[7];
    const float* bv  = (const float*)d_in[8];
    const float* Wo  = (const float*)d_in[9];
    const float* bo  = (const float*)d_in[10];
    const float* gam = (const float*)d_in[11];
    float* out = (float*)d_out;

    float* Qh = (float*)d_ws;                       // [B,H,S,DK] 16 MiB
    float* Kh = Qh + (size_t)NTOK * DM;             // 16 MiB
    float* Vh = Kh + (size_t)NTOK * DM;             // 16 MiB
    float* Ao = Vh + (size_t)NTOK * DM;             // [B,S,DM]  16 MiB

    const dim3 ggrid(16, 64), gblk(256);
    gemm_xwT<true ><<<ggrid, gblk, 0, stream>>>(q,  Wq, bq, Qh);
    gemm_xwT<true ><<<ggrid, gblk, 0, stream>>>(k,  Wk, bk, Kh);
    gemm_xwT<true ><<<ggrid, gblk, 0, stream>>>(v,  Wv, bv, Vh);
    attn_kernel<<<dim3(64 * 256), dim3(256), 0, stream>>>(Qh, Kh, Vh, gam, Ao);
    gemm_xwT<false><<<ggrid, gblk, 0, stream>>>(Ao, Wo, bo, out);
}

// Round 3
// 1477.603 us; speedup vs baseline: 1.0728x; 1.0728x over previous
//
#include <hip/hip_runtime.h>
#include <math.h>

#define BB 4
#define SS 1024
#define DM 1024
#define HH 16
#define DKK 64
#define NTOK (BB*SS)   // 4096
#define QT 16          // q-rows per attn block

// ============================================================
// GEMM: Y = X @ W^T + bias
// X: [4096,1024] rm, W: [1024,1024] rm. 128x128 tile, 512 thr,
// 8x4 micro-tile, BK=16.
// ============================================================
template<bool HEAD_OUT>
__global__ __launch_bounds__(512) void gemm_xwT(
    const float* __restrict__ X, const float* __restrict__ W,
    const float* __restrict__ bias, float* __restrict__ Y)
{
    __shared__ float Xs[16][132];   // [k][m]; 132*4=528B rows, 16B-aligned
    __shared__ float Ws[16][132];   // [k][o]

    const int tid = threadIdx.x;
    const int m0 = blockIdx.y * 128;
    const int o0 = blockIdx.x * 128;
    const int lr = tid >> 2;          // 0..127 tile row (loader)
    const int lk = (tid & 3) << 2;    // k offset 0,4,8,12
    const int tm = tid >> 5;          // 0..15 (8-row group)
    const int tn = tid & 31;          // 0..31 (4-col group)

    float acc[8][4] = {};

    for (int kt = 0; kt < 1024; kt += 16) {
        const float4 xa = *(const float4*)&X[(size_t)(m0 + lr) * 1024 + kt + lk];
        const float4 wa = *(const float4*)&W[(size_t)(o0 + lr) * 1024 + kt + lk];
        __syncthreads();   // previous iteration's LDS reads done
        Xs[lk+0][lr] = xa.x; Xs[lk+1][lr] = xa.y; Xs[lk+2][lr] = xa.z; Xs[lk+3][lr] = xa.w;
        Ws[lk+0][lr] = wa.x; Ws[lk+1][lr] = wa.y; Ws[lk+2][lr] = wa.z; Ws[lk+3][lr] = wa.w;
        __syncthreads();
        #pragma unroll
        for (int kk = 0; kk < 16; ++kk) {
            float a[8], b[4];
            *(float4*)&a[0] = *(const float4*)&Xs[kk][tm*8 + 0];  // 32-lane bcast
            *(float4*)&a[4] = *(const float4*)&Xs[kk][tm*8 + 4];
            *(float4*)&b[0] = *(const float4*)&Ws[kk][tn*4];      // 2-way dup, contiguous
            #pragma unroll
            for (int i = 0; i < 8; ++i)
                #pragma unroll
                for (int j = 0; j < 4; ++j)
                    acc[i][j] = fmaf(a[i], b[j], acc[i][j]);
        }
    }

    const float4 b4 = *(const float4*)&bias[o0 + tn*4];
    const float bj[4] = {b4.x, b4.y, b4.z, b4.w};
    #pragma unroll
    for (int i = 0; i < 8; ++i) {
        const int m = m0 + tm*8 + i;
        float4 o;
        o.x = acc[i][0] + bj[0]; o.y = acc[i][1] + bj[1];
        o.z = acc[i][2] + bj[2]; o.w = acc[i][3] + bj[3];
        if (HEAD_OUT) {
            const int b_ = m >> 10, s_ = m & 1023;
            const int oc = o0 + tn*4;             // 4-aligned, never crosses head
            const int h_ = oc >> 6, d_ = oc & 63;
            *(float4*)&Y[(((size_t)(b_*HH + h_))*SS + s_)*DKK + d_] = o;
        } else {
            *(float4*)&Y[(size_t)m*1024 + o0 + tn*4] = o;
        }
    }
}

// ============================================================
// Fused attention, 16 q-rows per block, 4 waves.
// Phase1: QK^T (K in regs, Q broadcast). Phase2: per-row
// softmax/cumsum/decay/softmax (wave owns 4 rows, interleaved
// float4 chunks = conflict-free). Phase3: PV with k split 4-way
// across waves, LDS partial reduction.
// ============================================================
__global__ __launch_bounds__(256) void attn_kernel(
    const float* __restrict__ Qh, const float* __restrict__ Kh,
    const float* __restrict__ Vh, const float* __restrict__ gammas,
    float* __restrict__ Ao)
{
    __shared__ float sS[QT][1024];   // 64 KB score rows
    __shared__ float sQ[QT][64];     // 4 KB

    const int tid  = threadIdx.x;
    const int lane = tid & 63;
    const int w    = tid >> 6;

    // XCD-bijective swizzle: 4096 blocks -> 512 contiguous per XCD
    const int bid = ((blockIdx.x & 7) << 9) | (blockIdx.x >> 3);
    const int bh  = bid >> 6;
    const int qt  = bid & 63;
    const int q0  = qt * QT;
    const int h   = bh & (HH - 1);
    const int b_  = bh >> 4;

    const float* Qb = Qh + (size_t)bh * SS * DKK;
    const float* Kb = Kh + (size_t)bh * SS * DKK;
    const float* Vb = Vh + (size_t)bh * SS * DKK;

    const float g = gammas[h];
    const float gamma = -(fmaxf(g, 0.f) + log1pf(expf(-fabsf(g))));

    {   // load Q tile (coalesced)
        const int r = tid >> 4, c4 = (tid & 15) << 2;
        *(float4*)&sQ[r][c4] = *(const float4*)&Qb[(size_t)(q0 + r)*DKK + c4];
    }
    __syncthreads();

    // ---------- phase 1: QK^T ----------
    #pragma unroll 1
    for (int i = 0; i < 4; ++i) {
        const int kk = i*256 + w*64 + lane;
        float4 kreg[16];
        #pragma unroll
        for (int c = 0; c < 16; ++c)
            kreg[c] = *(const float4*)&Kb[(size_t)kk*DKK + c*4];
        #pragma unroll
        for (int r = 0; r < QT; ++r) {
            float acc = 0.f;
            #pragma unroll
            for (int c = 0; c < 16; ++c) {
                const float4 q4 = *(const float4*)&sQ[r][c*4];  // broadcast, free
                acc = fmaf(kreg[c].x, q4.x, acc);
                acc = fmaf(kreg[c].y, q4.y, acc);
                acc = fmaf(kreg[c].z, q4.z, acc);
                acc = fmaf(kreg[c].w, q4.w, acc);
            }
            sS[r][kk] = acc * 0.125f;   // 1/sqrt(64); lane-contiguous write
        }
    }
    __syncthreads();

    // ---------- phase 2: per-row pipeline; wave w owns rows 4w..4w+3 ----------
    #pragma unroll 1
    for (int rr = 0; rr < 4; ++rr) {
        const int r = (w << 2) | rr;
        const int q = q0 + r;

        float sv[16], ex[16];
        #pragma unroll
        for (int seg = 0; seg < 4; ++seg) {
            const float4 t = *(const float4*)&sS[r][seg*256 + lane*4];  // conflict-free
            sv[seg*4+0] = t.x; sv[seg*4+1] = t.y; sv[seg*4+2] = t.z; sv[seg*4+3] = t.w;
        }
        // unmasked row max + sum(exp)  (reference softmaxes UNmasked scores)
        float m1 = -INFINITY;
        #pragma unroll
        for (int t = 0; t < 16; ++t) m1 = fmaxf(m1, sv[t]);
        #pragma unroll
        for (int off = 32; off; off >>= 1) m1 = fmaxf(m1, __shfl_xor(m1, off, 64));
        float s1 = 0.f;
        #pragma unroll
        for (int t = 0; t < 16; ++t) { ex[t] = expf(sv[t] - m1); s1 += ex[t]; }
        #pragma unroll
        for (int off = 32; off; off >>= 1) s1 += __shfl_xor(s1, off, 64);
        const float inv_s1 = 1.f / s1;

        // masked p, 4-segment carry scan (k = seg*256 + lane*4 + j)
        float dc[16];
        float carry = 0.f;
        #pragma unroll
        for (int seg = 0; seg < 4; ++seg) {
            float pf[4];
            float run = 0.f;
            #pragma unroll
            for (int j = 0; j < 4; ++j) {
                const int k = seg*256 + lane*4 + j;
                const float p = (k <= q) ? ex[seg*4+j] * inv_s1 : 0.f;
                run += p;
                pf[j] = run;
            }
            const float ls = run;
            float sc = ls;
            #pragma unroll
            for (int off = 1; off < 64; off <<= 1) {
                const float t = __shfl_up(sc, off, 64);
                if (lane >= off) sc += t;
            }
            const float segtot = __shfl(sc, 63, 64);
            const float excl = sc - ls;
            #pragma unroll
            for (int j = 0; j < 4; ++j) dc[seg*4+j] = carry + excl + pf[j];
            carry += segtot;
        }
        const float total = carry;   // disttotal

        // distance decay -> masked scores
        #pragma unroll
        for (int seg = 0; seg < 4; ++seg) {
            #pragma unroll
            for (int j = 0; j < 4; ++j) {
                const int k = seg*256 + lane*4 + j;
                const int t = seg*4 + j;
                if (k <= q) {
                    const float dsc = sqrtf(fmaxf((total - dc[t]) * (float)(q - k), 0.f));
                    const float te  = fminf(fmaxf(__expf(dsc * gamma), 1e-5f), 1e5f);
                    sv[t] = sv[t] * te;
                } else {
                    sv[t] = -INFINITY;
                }
            }
        }

        // masked softmax
        float m2 = -INFINITY;
        #pragma unroll
        for (int t = 0; t < 16; ++t) m2 = fmaxf(m2, sv[t]);
        #pragma unroll
        for (int off = 32; off; off >>= 1) m2 = fmaxf(m2, __shfl_xor(m2, off, 64));
        float s2 = 0.f;
        #pragma unroll
        for (int t = 0; t < 16; ++t) { ex[t] = __expf(sv[t] - m2); s2 += ex[t]; }
        #pragma unroll
        for (int off = 32; off; off >>= 1) s2 += __shfl_xor(s2, off, 64);
        const float inv2 = 1.f / s2;

        #pragma unroll
        for (int seg = 0; seg < 4; ++seg) {
            float4 o;
            o.x = ex[seg*4+0]*inv2; o.y = ex[seg*4+1]*inv2;
            o.z = ex[seg*4+2]*inv2; o.w = ex[seg*4+3]*inv2;
            *(float4*)&sS[r][seg*256 + lane*4] = o;   // conflict-free
        }
    }
    __syncthreads();

    // ---------- phase 3: PV, k split 4-way across waves ----------
    const int kmax = q0 + QT;   // P==0 beyond each row's q
    float pacc[16];
    #pragma unroll
    for (int r = 0; r < 16; ++r) pacc[r] = 0.f;

    #pragma unroll 1
    for (int k4 = w*4; k4 < kmax; k4 += 16) {
        const float va = Vb[(size_t)(k4+0)*DKK + lane];   // coalesced 256B
        const float vb = Vb[(size_t)(k4+1)*DKK + lane];
        const float vc = Vb[(size_t)(k4+2)*DKK + lane];
        const float vd = Vb[(size_t)(k4+3)*DKK + lane];
        #pragma unroll
        for (int r = 0; r < 16; ++r) {
            const float4 p4 = *(const float4*)&sS[r][k4];  // b128 broadcast
            pacc[r] = fmaf(p4.x, va, pacc[r]);
            pacc[r] = fmaf(p4.y, vb, pacc[r]);
            pacc[r] = fmaf(p4.z, vc, pacc[r]);
            pacc[r] = fmaf(p4.w, vd, pacc[r]);
        }
    }
    __syncthreads();   // everyone done reading P -> sS reusable as scratch

    float* scr = &sS[0][0];
    #pragma unroll
    for (int r = 0; r < 16; ++r)
        scr[(w*16 + r)*64 + lane] = pacc[r];
    __syncthreads();

    {   // reduce 4 wave-partials, write concat layout [B,S,DM]
        const int r = tid >> 4, c4 = (tid & 15) << 2;
        const float4 s0 = *(const float4*)&scr[( 0 + r)*64 + c4];
        const float4 s1_ = *(const float4*)&scr[(16 + r)*64 + c4];
        const float4 s2_ = *(const float4*)&scr[(32 + r)*64 + c4];
        const float4 s3_ = *(const float4*)&scr[(48 + r)*64 + c4];
        float4 o;
        o.x = s0.x + s1_.x + s2_.x + s3_.x;
        o.y = s0.y + s1_.y + s2_.y + s3_.y;
        o.z = s0.z + s1_.z + s2_.z + s3_.z;
        o.w = s0.w + s1_.w + s2_.w + s3_.w;
        *(float4*)&Ao[((size_t)(b_*SS + q0 + r))*DM + h*DKK + c4] = o;
    }
}

// ============================================================
extern "C" void kernel_launch(void* const* d_in, const int* in_sizes, int n_in,
                              void* d_out, int out_size, void* d_ws, size_t ws_size,
                              hipStream_t stream)
{
    (void)in_sizes; (void)n_in; (void)out_size; (void)ws_size;

    const float* q   = (const float*)d_in[0];
    const float* k   = (const float*)d_in[1];
    const float* v   = (const float*)d_in[2];
    const float* Wq  = (const float*)d_in[3];
    const float* bq  = (const float*)d_in[4];
    const float* Wk  = (const float*)d_in[5];
    const float* bk  = (const float*)d_in[6];
    const float* Wv  = (const float*)d_in[7];
    const float* bv  = (const float*)d_in[8];
    const float* Wo  = (const float*)d_in[9];
    const float* bo  = (const float*)d_in[10];
    const float* gam = (const float*)d_in[11];
    float* out = (float*)d_out;

    float* Qh = (float*)d_ws;                       // [B,H,S,DK] 16 MiB
    float* Kh = Qh + (size_t)NTOK * DM;             // 16 MiB
    float* Vh = Kh + (size_t)NTOK * DM;             // 16 MiB
    float* Ao = Vh + (size_t)NTOK * DM;             // [B,S,DM]  16 MiB

    const dim3 ggrid(8, 32), gblk(512);
    gemm_xwT<true ><<<ggrid, gblk, 0, stream>>>(q,  Wq, bq, Qh);
    gemm_xwT<true ><<<ggrid, gblk, 0, stream>>>(k,  Wk, bk, Kh);
    gemm_xwT<true ><<<ggrid, gblk, 0, stream>>>(v,  Wv, bv, Vh);
    attn_kernel<<<dim3(4096), dim3(256), 0, stream>>>(Qh, Kh, Vh, gam, Ao);
    gemm_xwT<false><<<ggrid, gblk, 0, stream>>>(Ao, Wo, bo, out);
}